// Round 8
// baseline (733.257 us; speedup 1.0000x reference)
//
#include <hip/hip_runtime.h>

#define L_SZ 2048
#define DIM_SZ 512
#define SPADK 1088   // mp logits row: 513 mag + 513 phase + 62 pad (fp32)
#define ATK 544      // symmetric iSTFT GEMM K: 513 padded to 17*32
#define ATM 640      // symmetric iSTFT GEMM M: 513 padded to 5*128 (store-clipped at 576)
#define ATMV 576     // valid (write) M bound
#define ATSZ (ATM * ATK)       // logical elems per basis table
#define ATROW (2 * ATK)        // packed row pitch in ushorts (hi/lo interleaved)
#define ATSZ_PK (ATM * ATROW)  // packed ushorts per basis table

typedef __attribute__((ext_vector_type(8))) short bfx8;
typedef __attribute__((ext_vector_type(4))) float f32x4;

// round-to-nearest-even fp32 -> bf16 helpers
__device__ __forceinline__ ushort f2bf(float v) {
  unsigned u = __float_as_uint(v);
  unsigned r = u + 0x7FFFu + ((u >> 16) & 1u);
  return (ushort)(r >> 16);
}
__device__ __forceinline__ float bfhi_f(float v) {
  unsigned u = __float_as_uint(v);
  unsigned r = (u + 0x7FFFu + ((u >> 16) & 1u)) & 0xFFFF0000u;
  return __uint_as_float(r);
}

// async global->LDS 16B DMA (wave-uniform LDS base + lane*16)
__device__ __forceinline__ void gl_lds16(const void* g, void* l) {
  __builtin_amdgcn_global_load_lds(
      (const __attribute__((address_space(1))) unsigned int*)(uintptr_t)g,
      (__attribute__((address_space(3))) unsigned int*)(uintptr_t)l, 16, 0, 0);
}

// packed hi/lo write helper (scalar producers): row-pitch 2K ushorts
__device__ __forceinline__ void pk_store(ushort* base, size_t row, int pitch2k, int k,
                                         float v) {
  size_t o = row * (size_t)pitch2k + (size_t)((k >> 3) * 16 + (k & 7));
  float hf = bfhi_f(v);
  base[o] = (ushort)(__float_as_uint(hf) >> 16);
  base[o + 8] = f2bf(v - hf);
}

// ---------------- per-batch LoRA factor GEMVs: out[b*rows + r] = dot(mat[r], g[b]) ----
// tR > 0: rows = K*R with r fastest; write TRANSPOSED out[b][r][k] (k = row/tR).
__global__ __launch_bounds__(256) void lora_vec_k(const float* __restrict__ mat, int rows,
                                                  const float* __restrict__ g,
                                                  float* __restrict__ out,
                                                  int tK, int tR) {
  __shared__ float gs[2048];
  int tid = threadIdx.x;
#pragma unroll
  for (int i = 0; i < 8; i++) gs[i * 256 + tid] = g[i * 256 + tid];
  __syncthreads();
  int row = blockIdx.x * 4 + (tid >> 6);
  if (row >= rows) return;
  int lane = tid & 63;
  float4 mv = *(const float4*)(mat + (size_t)row * 256 + lane * 4);
  float p[8];
#pragma unroll
  for (int b = 0; b < 8; b++) {
    const float* gb = gs + b * 256 + lane * 4;
    p[b] = mv.x * gb[0] + mv.y * gb[1] + mv.z * gb[2] + mv.w * gb[3];
  }
#pragma unroll
  for (int b = 0; b < 8; b++) {
    float v = p[b];
#pragma unroll
    for (int off = 32; off > 0; off >>= 1) v += __shfl_down(v, off, 64);
    if (lane == 0) {
      size_t o;
      if (tR > 0) {
        int kk = row / tR, rr = row - kk * tR;
        o = ((size_t)b * tR + rr) * tK + kk;
      } else {
        o = (size_t)b * rows + row;
      }
      out[o] = v;
    }
  }
}

// --- W_eff[b][m][k] = W[m][k] + sum_r aout[b][r][m] * ain_t[b][r][k]; packed bf16 out.
__global__ __launch_bounds__(256) void weff_k(const float* __restrict__ W,
                                              const float* __restrict__ aint,
                                              const float* __restrict__ aout,
                                              ushort* __restrict__ opk, int M, int Mpad,
                                              int K, int R) {
  const int b = blockIdx.z;
  const int kc8 = K >> 3;
  int flat = blockIdx.x * 256 + threadIdx.x;  // over Mpad * K/8 (exact multiple)
  int m = flat / kc8, kc = flat - m * kc8;
  float acc[8] = {};
  if (m < M) {
    const float4* wv = (const float4*)(W + (size_t)m * K + kc * 8);
    float4 w0 = wv[0], w1 = wv[1];
    acc[0] = w0.x; acc[1] = w0.y; acc[2] = w0.z; acc[3] = w0.w;
    acc[4] = w1.x; acc[5] = w1.y; acc[6] = w1.z; acc[7] = w1.w;
    const float* ai = aint + (size_t)b * R * K + kc * 8;
    const float* ao = aout + (size_t)b * M * R + m;
    for (int r = 0; r < R; r++) {
      float aor = ao[(size_t)r * M];
      const float4* av = (const float4*)(ai + (size_t)r * K);
      float4 a0 = av[0], a1 = av[1];
      acc[0] += aor * a0.x; acc[1] += aor * a0.y;
      acc[2] += aor * a0.z; acc[3] += aor * a0.w;
      acc[4] += aor * a1.x; acc[5] += aor * a1.y;
      acc[6] += aor * a1.z; acc[7] += aor * a1.w;
    }
  }
  unsigned hw[4], lw[4];
#pragma unroll
  for (int i = 0; i < 4; i++) {
    float h0 = bfhi_f(acc[2 * i]), h1 = bfhi_f(acc[2 * i + 1]);
    unsigned u0 = __float_as_uint(h0) >> 16, u1 = __float_as_uint(h1) >> 16;
    hw[i] = u0 | (u1 << 16);
    unsigned l0 = f2bf(acc[2 * i] - h0), l1 = f2bf(acc[2 * i + 1] - h1);
    lw[i] = l0 | (l1 << 16);
  }
  ushort* o = opk + ((size_t)b * Mpad + m) * (size_t)(2 * K) + kc * 16;
  *(uint4*)(o) = make_uint4(hw[0], hw[1], hw[2], hw[3]);
  *(uint4*)(o + 8) = make_uint4(lw[0], lw[1], lw[2], lw[3]);
}

// -- causal depthwise conv -> packed h0: h0[b][t][c] = sum_k w[c][k]*x[b][c][t-k] --
__global__ __launch_bounds__(256) void dconv_k(const float* __restrict__ x,
                                               const float* __restrict__ w,
                                               const float* __restrict__ bias,
                                               ushort* __restrict__ h0pk) {
  const int t0 = blockIdx.x * 64;
  const int c0 = blockIdx.y * 64;
  const int b = blockIdx.z;
  const int tid = threadIdx.x;
  __shared__ float xs[64 * 68];
  const float* xb = x + ((size_t)b * DIM_SZ + c0) * L_SZ;
#pragma unroll
  for (int i = 0; i < 17; i++) {
    int flat = i * 256 + tid;  // 0..4351 = 64*68
    int c = flat / 68, tt = flat % 68;
    int t = t0 - 4 + tt;
    xs[c * 68 + tt] = (t >= 0) ? xb[(size_t)c * L_SZ + t] : 0.0f;
  }
  __syncthreads();
  int c = tid & 63;
  int tb = (tid >> 6) * 16;
  float wl[5];
#pragma unroll
  for (int k = 0; k < 5; k++) wl[k] = w[(c0 + c) * 5 + k];
  float bl = bias[c0 + c];
#pragma unroll
  for (int j = 0; j < 16; j++) {
    int t = tb + j;
    float acc = bl;
#pragma unroll
    for (int k = 0; k < 5; k++) acc += wl[k] * xs[c * 68 + t + 4 - k];
    pk_store(h0pk, (size_t)b * L_SZ + t0 + t, 2 * DIM_SZ, c0 + c, acc);
  }
}

// ---- symmetric istft basis tables (window+sideband folded), packed bf16 hi/lo ----
__global__ __launch_bounds__(256) void atab2_k(ushort* __restrict__ tab,
                                               double* __restrict__ win) {
  int flat = blockIdx.x * 256 + threadIdx.x;  // over 2*640*544 = 696320
  int table = flat / ATSZ;
  int rem = flat - table * ATSZ;
  int n = rem / ATK, k = rem % ATK;
  const double W = 6.283185307179586476925287 / 1024.0;
  float val = 0.f;
  if (n <= 512 && k <= 512) {
    double wn = 0.5 * (1.0 - cos(W * (double)n));
    int mm = (k * n) & 1023;
    if (table == 0) {
      double wk = (k == 0 || k == 512) ? 1.0 : 2.0;
      val = (float)(wn * wk * cos(W * (double)mm));
    } else {
      val = (float)(wn * 2.0 * sin(W * (double)mm));
    }
  }
  pk_store(tab + (size_t)table * ATSZ_PK, (size_t)n, ATROW, k, val);
  if (flat < 1024) win[flat] = 0.5 * (1.0 - cos(W * (double)flat));
}

// ---- S prep: read fp32 (m,p) logits, emit packed Sre, Sim ----
__global__ __launch_bounds__(256) void sprep2_k(const float* __restrict__ mp,
                                                ushort* __restrict__ Sre,
                                                ushort* __restrict__ Sim) {
  size_t flat = (size_t)blockIdx.x * 256 + threadIdx.x;  // over 8*2048*544
  size_t row = flat / ATK;
  int k = (int)(flat % ATK);
  float re = 0.f, im = 0.f;
  if (k < 513) {
    const float* r = mp + row * SPADK;
    float m = r[k], p = r[513 + k];
    float mag = fminf(expf(m), 100.0f);
    re = mag * cosf(p);
    im = mag * sinf(p);
  }
  pk_store(Sre, row, ATROW, k, re);
  pk_store(Sim, row, ATROW, k, im);
}

// ---- bf16 3-term-split MFMA GEMM, m97 structure; MT = block m-tile (128 or 256).
//  Block tile MT x 128, 4 waves in 2x2, wave tile (MT/2) x 64 (NH = MT/128 m-halves).
//  global_load_lds(16B) staging, both-sides XOR swizzle (chunk ^ (row&7)).
template <int MT, bool GELU, bool OUTBF>
__global__ __launch_bounds__(256, 2) void gemm_pk(
    const ushort* __restrict__ Apk, size_t a_bs,
    const ushort* __restrict__ Bpk, size_t b_bs,
    const float* __restrict__ bias, int Mb,
    float* __restrict__ Cf, ushort* __restrict__ Cpk, size_t c_bs, int ldc,
    int Mst, int K) {
  constexpr int NH = MT / 128;      // m-halves per wave
  const int b = blockIdx.z;
  const int m0 = blockIdx.x * MT;
  const int t0 = blockIdx.y * 128;
  const int tid = threadIdx.x;
  const int l = tid & 63;
  const int w = tid >> 6;
  const int wm = (w & 1) * (MT / 2);
  const int wt = (w >> 1) * 64;
  const int tr = l & 15;   // frag row within 16; also output col t
  const int ks = l >> 4;   // k-slot (8 bf16); also output row-quad selector
  __shared__ ushort As[MT * 64];
  __shared__ ushort Bs[128 * 64];
  const int pitch = 2 * K;
  const int sr = l >> 3;         // lds row within 8-row group
  const int sc = l & 7;          // lds 16B-chunk within row
  const int scs = sc ^ sr;       // pre-swizzled global chunk
  const ushort* gA = Apk + (size_t)b * a_bs + (size_t)(m0 + w * (MT / 4) + sr) * pitch + scs * 8;
  const ushort* gB = Bpk + (size_t)b * b_bs + (size_t)(t0 + w * 32 + sr) * pitch + scs * 8;
  ushort* lA = As + w * (MT / 4) * 64;
  ushort* lB = Bs + w * 32 * 64;
  const int swz = tr & 7;
  const int ch_hi = ((2 * ks) ^ swz) * 8;
  const int ch_lo = ((2 * ks + 1) ^ swz) * 8;
  const int aBase = (wm + tr) * 64;
  const int bBase = (wt + tr) * 64;
  f32x4 acc[NH][4][4];
#pragma unroll
  for (int h = 0; h < NH; h++)
#pragma unroll
    for (int i = 0; i < 4; i++)
#pragma unroll
      for (int j = 0; j < 4; j++) acc[h][i][j] = (f32x4){0.f, 0.f, 0.f, 0.f};
  for (int kt = 0; kt < K; kt += 32) {
    if (kt) __syncthreads();
    const ushort* ga = gA + kt * 2;
    const ushort* gb = gB + kt * 2;
#pragma unroll
    for (int i = 0; i < MT / 32; i++)
      gl_lds16(ga + (size_t)(i * 8) * pitch, lA + i * 8 * 64);
#pragma unroll
    for (int i = 0; i < 4; i++)
      gl_lds16(gb + (size_t)(i * 8) * pitch, lB + i * 8 * 64);
    __syncthreads();
    bfx8 bh[4], bl[4];
#pragma unroll
    for (int f = 0; f < 4; f++) bh[f] = *(const bfx8*)(Bs + bBase + f * 1024 + ch_hi);
#pragma unroll
    for (int f = 0; f < 4; f++) bl[f] = *(const bfx8*)(Bs + bBase + f * 1024 + ch_lo);
#pragma unroll
    for (int h = 0; h < NH; h++) {
      bfx8 ah[4], al[4];
#pragma unroll
      for (int f = 0; f < 4; f++) ah[f] = *(const bfx8*)(As + aBase + h * 4096 + f * 1024 + ch_hi);
#pragma unroll
      for (int fi = 0; fi < 4; fi++)
#pragma unroll
        for (int fj = 0; fj < 4; fj++)
          acc[h][fi][fj] = __builtin_amdgcn_mfma_f32_16x16x32_bf16(ah[fi], bh[fj], acc[h][fi][fj], 0, 0, 0);
#pragma unroll
      for (int fi = 0; fi < 4; fi++)
#pragma unroll
        for (int fj = 0; fj < 4; fj++)
          acc[h][fi][fj] = __builtin_amdgcn_mfma_f32_16x16x32_bf16(ah[fi], bl[fj], acc[h][fi][fj], 0, 0, 0);
#pragma unroll
      for (int f = 0; f < 4; f++) al[f] = *(const bfx8*)(As + aBase + h * 4096 + f * 1024 + ch_lo);
#pragma unroll
      for (int fi = 0; fi < 4; fi++)
#pragma unroll
        for (int fj = 0; fj < 4; fj++)
          acc[h][fi][fj] = __builtin_amdgcn_mfma_f32_16x16x32_bf16(al[fi], bh[fj], acc[h][fi][fj], 0, 0, 0);
    }
  }
  const int orow = ks * 4;
#pragma unroll
  for (int h = 0; h < NH; h++) {
#pragma unroll
    for (int fi = 0; fi < 4; fi++) {
      int m = m0 + wm + h * 64 + fi * 16 + orow;
      if (m >= Mst) continue;
#pragma unroll
      for (int fj = 0; fj < 4; fj++) {
        int t = t0 + wt + fj * 16 + tr;
        float o[4];
#pragma unroll
        for (int i = 0; i < 4; i++) {
          float xv = acc[h][fi][fj][i];
          if (bias != nullptr && (m + i) < Mb) xv += bias[m + i];
          if (GELU) xv = 0.5f * xv * (1.0f + erff(xv * 0.70710678118654752f));
          o[i] = xv;
        }
        if (OUTBF) {
          size_t base = (size_t)b * c_bs + (size_t)t * (2 * ldc) + ((m >> 3) * 16 + (m & 7));
          ushort hb[4], lb[4];
#pragma unroll
          for (int i = 0; i < 4; i++) {
            float hf = bfhi_f(o[i]);
            hb[i] = (ushort)(__float_as_uint(hf) >> 16);
            lb[i] = f2bf(o[i] - hf);
          }
          *(ushort4*)(Cpk + base) = make_ushort4(hb[0], hb[1], hb[2], hb[3]);
          *(ushort4*)(Cpk + base + 8) = make_ushort4(lb[0], lb[1], lb[2], lb[3]);
        } else {
          *(float4*)(Cf + (size_t)b * c_bs + (size_t)t * ldc + m) =
              make_float4(o[0], o[1], o[2], o[3]);
        }
      }
    }
  }
}

// ------- overlap-add + env normalize + crop, with symmetric frame reconstruction ----
__global__ __launch_bounds__(256) void ola_k(const float* __restrict__ CD,
                                             const double* __restrict__ win,
                                             float* __restrict__ out) {
  size_t flat = (size_t)blockIdx.x * 256 + threadIdx.x;  // over 8*524288
  int b = (int)(flat >> 19);
  int t = (int)(flat & 524287);
  int g = t + 384;  // PAD
  int r = g & 255, q4 = g >> 8;
  double acc = 0.0, env = 0.0;
#pragma unroll
  for (int q = 0; q < 4; q++) {
    int tau = q4 - q;
    int n = r + 256 * q;
    if (tau >= 0 && tau < 2048) {
      double w = win[n];
      int np = (n <= 512) ? n : 1024 - n;
      double sgn = (n <= 512) ? -1.0 : 1.0;
      const float* base = CD + ((size_t)b * 2048 + tau) * 1152 + np;
      acc += (double)base[0] + sgn * (double)base[576];
      env = fma(w, w, env);
    }
  }
  out[flat] = (float)(acc / (env * 1024.0));
}

extern "C" void kernel_launch(void* const* d_in, const int* in_sizes, int n_in, void* d_out,
                              int out_size, void* d_ws, size_t ws_size, hipStream_t stream) {
  (void)in_sizes; (void)n_in; (void)out_size; (void)ws_size;
  const float* x       = (const float*)d_in[0];
  const float* g_out   = (const float*)d_in[1];
  const float* dconv_w = (const float*)d_in[2];
  const float* dconv_b = (const float*)d_in[3];
  const float* p1_w    = (const float*)d_in[4];
  const float* p1_b    = (const float*)d_in[5];
  const float* p1_ain  = (const float*)d_in[6];
  const float* p1_aout = (const float*)d_in[7];
  const float* p2_w    = (const float*)d_in[8];
  const float* p2_b    = (const float*)d_in[9];
  const float* p2_ain  = (const float*)d_in[10];
  const float* p2_aout = (const float*)d_in[11];
  const float* out_w   = (const float*)d_in[12];
  const float* out_b   = (const float*)d_in[13];
  const float* out_ain = (const float*)d_in[14];
  const float* out_aout= (const float*)d_in[15];

  // Workspace: front tables + arena with time-shared slots; peak ~177 MB < proven 192.3.
  char* ws = (char*)d_ws;
  float* ain1  = (float*)(ws + 0);         // transposed [b][12][512]
  float* aout1 = (float*)(ws + 196608);
  float* ain2  = (float*)(ws + 786432);    // transposed [b][12][1536]
  float* aout2 = (float*)(ws + 1376256);
  float* ain3  = (float*)(ws + 1572864);   // transposed [b][16][512]
  float* aout3 = (float*)(ws + 1835008);
  ushort* tab  = (ushort*)(ws + 2360320);  // 2 tables * 640*1088*2 B
  double* win  = (double*)(ws + 5145600);
  char*  arena = ws + 5153792;
  ushort* h1  = (ushort*)(arena + 0);
  float*  mp  = (float*)(arena + 0);
  float*  CD  = (float*)(arena + 0);
  ushort* h0  = (ushort*)(arena + 100663296);
  ushort* h2  = (ushort*)(arena + 100663296);
  ushort* w1  = (ushort*)(arena + 134217728);
  ushort* w2  = (ushort*)(arena + 134217728);
  ushort* w3  = (ushort*)(arena + 134217728);   // 8*1280*1024*2 = 21.0 MB (Mpad 1280)
  ushort* Sre = (ushort*)(arena + 100663296);
  ushort* Sim = (ushort*)(arena + 136314880);

  lora_vec_k<<<1536, 256, 0, stream>>>(p1_ain, 6144, g_out, ain1, 512, 12);
  lora_vec_k<<<4608, 256, 0, stream>>>(p1_aout, 18432, g_out, aout1, 0, 0);
  lora_vec_k<<<4608, 256, 0, stream>>>(p2_ain, 18432, g_out, ain2, 1536, 12);
  lora_vec_k<<<1536, 256, 0, stream>>>(p2_aout, 6144, g_out, aout2, 0, 0);
  lora_vec_k<<<2048, 256, 0, stream>>>(out_ain, 8192, g_out, ain3, 512, 16);
  lora_vec_k<<<4104, 256, 0, stream>>>(out_aout, 16416, g_out, aout3, 0, 0);
  atab2_k<<<2720, 256, 0, stream>>>(tab, win);
  dconv_k<<<dim3(32, 8, 8), 256, 0, stream>>>(x, dconv_w, dconv_b, h0);

  // layer 1: h1 = gelu(weff1 . h0 + b1)   (MT=256 tile)
  weff_k<<<dim3(384, 1, 8), 256, 0, stream>>>(p1_w, ain1, aout1, w1, 1536, 1536, 512, 12);
  gemm_pk<256, true, true><<<dim3(6, 16, 8), 256, 0, stream>>>(
      w1, (size_t)1536 * 1024, h0, (size_t)2048 * 1024, p1_b, 1536,
      nullptr, h1, (size_t)2048 * 3072, 1536, 1536, 512);

  // layer 2: h2 = gelu(weff2 . h1 + b2)   (M=512 -> keep MT=128 for block count)
  weff_k<<<dim3(384, 1, 8), 256, 0, stream>>>(p2_w, ain2, aout2, w2, 512, 512, 1536, 12);
  gemm_pk<128, true, true><<<dim3(4, 16, 8), 256, 0, stream>>>(
      w2, (size_t)512 * 3072, h1, (size_t)2048 * 3072, p2_b, 512,
      nullptr, h2, (size_t)2048 * 1024, 512, 512, 1536);

  // output projection: mp = weff3 . h2 + out_b  (fp32 out; Mpad 1280 for MT=256)
  weff_k<<<dim3(320, 1, 8), 256, 0, stream>>>(out_w, ain3, aout3, w3, 1026, 1280, 512, 16);
  gemm_pk<256, false, false><<<dim3(5, 16, 8), 256, 0, stream>>>(
      w3, (size_t)1280 * 1024, h2, (size_t)2048 * 1024, out_b, 1026,
      mp, nullptr, (size_t)2048 * SPADK, SPADK, SPADK, 512);

  sprep2_k<<<34816, 256, 0, stream>>>(mp, Sre, Sim);
  // cos-part -> CD[:, :, 0:576], sin-part -> CD[:, :, 576:1152]  (MT=128, ATM=640)
  gemm_pk<128, false, false><<<dim3(5, 16, 8), 256, 0, stream>>>(
      tab, (size_t)0, Sre, (size_t)2048 * ATROW, nullptr, 0,
      CD, nullptr, (size_t)2048 * 1152, 1152, ATMV, ATK);
  gemm_pk<128, false, false><<<dim3(5, 16, 8), 256, 0, stream>>>(
      tab + ATSZ_PK, (size_t)0, Sim, (size_t)2048 * ATROW, nullptr, 0,
      CD + 576, nullptr, (size_t)2048 * 1152, 1152, ATMV, ATK);
  ola_k<<<16384, 256, 0, stream>>>(CD, win, (float*)d_out);
}

// Round 11
// 719.149 us; speedup vs baseline: 1.0196x; 1.0196x over previous
//
#include <hip/hip_runtime.h>

#define L_SZ 2048
#define DIM_SZ 512
#define SPADK 1088   // mp logits row: 513 mag + 513 phase + 62 pad (fp32)
#define ATK 544      // symmetric iSTFT GEMM K: 513 padded to 17*32
#define ATM 640      // symmetric iSTFT GEMM M: 513 padded (store-clipped at 576)
#define ATMV 576     // valid (write) M bound
#define ATSZ (ATM * ATK)       // logical elems per basis table
#define ATROW (2 * ATK)        // packed row pitch in ushorts (hi/lo interleaved)
#define ATSZ_PK (ATM * ATROW)  // packed ushorts per basis table

typedef __attribute__((ext_vector_type(8))) short bfx8;
typedef __attribute__((ext_vector_type(4))) float f32x4;

// round-to-nearest-even fp32 -> bf16 helpers
__device__ __forceinline__ ushort f2bf(float v) {
  unsigned u = __float_as_uint(v);
  unsigned r = u + 0x7FFFu + ((u >> 16) & 1u);
  return (ushort)(r >> 16);
}
__device__ __forceinline__ float bfhi_f(float v) {
  unsigned u = __float_as_uint(v);
  unsigned r = (u + 0x7FFFu + ((u >> 16) & 1u)) & 0xFFFF0000u;
  return __uint_as_float(r);
}

// async global->LDS 16B DMA (wave-uniform LDS base + lane*16)
__device__ __forceinline__ void gl_lds16(const void* g, void* l) {
  __builtin_amdgcn_global_load_lds(
      (const __attribute__((address_space(1))) unsigned int*)(uintptr_t)g,
      (__attribute__((address_space(3))) unsigned int*)(uintptr_t)l, 16, 0, 0);
}

// packed hi/lo write helper (scalar producers): row-pitch 2K ushorts
__device__ __forceinline__ void pk_store(ushort* base, size_t row, int pitch2k, int k,
                                         float v) {
  size_t o = row * (size_t)pitch2k + (size_t)((k >> 3) * 16 + (k & 7));
  float hf = bfhi_f(v);
  base[o] = (ushort)(__float_as_uint(hf) >> 16);
  base[o + 8] = f2bf(v - hf);
}

// ---------------- per-batch LoRA factor GEMVs: out[b*rows + r] = dot(mat[r], g[b]) ----
// tR > 0: rows = K*R with r fastest; write TRANSPOSED out[b][r][k] (k = row/tR).
__global__ __launch_bounds__(256) void lora_vec_k(const float* __restrict__ mat, int rows,
                                                  const float* __restrict__ g,
                                                  float* __restrict__ out,
                                                  int tK, int tR) {
  __shared__ float gs[2048];
  int tid = threadIdx.x;
#pragma unroll
  for (int i = 0; i < 8; i++) gs[i * 256 + tid] = g[i * 256 + tid];
  __syncthreads();
  int row = blockIdx.x * 4 + (tid >> 6);
  if (row >= rows) return;
  int lane = tid & 63;
  float4 mv = *(const float4*)(mat + (size_t)row * 256 + lane * 4);
  float p[8];
#pragma unroll
  for (int b = 0; b < 8; b++) {
    const float* gb = gs + b * 256 + lane * 4;
    p[b] = mv.x * gb[0] + mv.y * gb[1] + mv.z * gb[2] + mv.w * gb[3];
  }
#pragma unroll
  for (int b = 0; b < 8; b++) {
    float v = p[b];
#pragma unroll
    for (int off = 32; off > 0; off >>= 1) v += __shfl_down(v, off, 64);
    if (lane == 0) {
      size_t o;
      if (tR > 0) {
        int kk = row / tR, rr = row - kk * tR;
        o = ((size_t)b * tR + rr) * tK + kk;
      } else {
        o = (size_t)b * rows + row;
      }
      out[o] = v;
    }
  }
}

// --- W_eff[b][m][k] = W[m][k] + sum_r aout[b][r][m] * ain_t[b][r][k]; packed bf16 out.
__global__ __launch_bounds__(256) void weff_k(const float* __restrict__ W,
                                              const float* __restrict__ aint,
                                              const float* __restrict__ aout,
                                              ushort* __restrict__ opk, int M, int Mpad,
                                              int K, int R) {
  const int b = blockIdx.z;
  const int kc8 = K >> 3;
  int flat = blockIdx.x * 256 + threadIdx.x;  // over Mpad * K/8 (exact multiple)
  int m = flat / kc8, kc = flat - m * kc8;
  float acc[8] = {};
  if (m < M) {
    const float4* wv = (const float4*)(W + (size_t)m * K + kc * 8);
    float4 w0 = wv[0], w1 = wv[1];
    acc[0] = w0.x; acc[1] = w0.y; acc[2] = w0.z; acc[3] = w0.w;
    acc[4] = w1.x; acc[5] = w1.y; acc[6] = w1.z; acc[7] = w1.w;
    const float* ai = aint + (size_t)b * R * K + kc * 8;
    const float* ao = aout + (size_t)b * M * R + m;
    for (int r = 0; r < R; r++) {
      float aor = ao[(size_t)r * M];
      const float4* av = (const float4*)(ai + (size_t)r * K);
      float4 a0 = av[0], a1 = av[1];
      acc[0] += aor * a0.x; acc[1] += aor * a0.y;
      acc[2] += aor * a0.z; acc[3] += aor * a0.w;
      acc[4] += aor * a1.x; acc[5] += aor * a1.y;
      acc[6] += aor * a1.z; acc[7] += aor * a1.w;
    }
  }
  unsigned hw[4], lw[4];
#pragma unroll
  for (int i = 0; i < 4; i++) {
    float h0 = bfhi_f(acc[2 * i]), h1 = bfhi_f(acc[2 * i + 1]);
    unsigned u0 = __float_as_uint(h0) >> 16, u1 = __float_as_uint(h1) >> 16;
    hw[i] = u0 | (u1 << 16);
    unsigned l0 = f2bf(acc[2 * i] - h0), l1 = f2bf(acc[2 * i + 1] - h1);
    lw[i] = l0 | (l1 << 16);
  }
  ushort* o = opk + ((size_t)b * Mpad + m) * (size_t)(2 * K) + kc * 16;
  *(uint4*)(o) = make_uint4(hw[0], hw[1], hw[2], hw[3]);
  *(uint4*)(o + 8) = make_uint4(lw[0], lw[1], lw[2], lw[3]);
}

// -- causal depthwise conv -> packed h0: h0[b][t][c] = sum_k w[c][k]*x[b][c][t-k] --
__global__ __launch_bounds__(256) void dconv_k(const float* __restrict__ x,
                                               const float* __restrict__ w,
                                               const float* __restrict__ bias,
                                               ushort* __restrict__ h0pk) {
  const int t0 = blockIdx.x * 64;
  const int c0 = blockIdx.y * 64;
  const int b = blockIdx.z;
  const int tid = threadIdx.x;
  __shared__ float xs[64 * 68];
  const float* xb = x + ((size_t)b * DIM_SZ + c0) * L_SZ;
#pragma unroll
  for (int i = 0; i < 17; i++) {
    int flat = i * 256 + tid;  // 0..4351 = 64*68
    int c = flat / 68, tt = flat % 68;
    int t = t0 - 4 + tt;
    xs[c * 68 + tt] = (t >= 0) ? xb[(size_t)c * L_SZ + t] : 0.0f;
  }
  __syncthreads();
  int c = tid & 63;
  int tb = (tid >> 6) * 16;
  float wl[5];
#pragma unroll
  for (int k = 0; k < 5; k++) wl[k] = w[(c0 + c) * 5 + k];
  float bl = bias[c0 + c];
#pragma unroll
  for (int j = 0; j < 16; j++) {
    int t = tb + j;
    float acc = bl;
#pragma unroll
    for (int k = 0; k < 5; k++) acc += wl[k] * xs[c * 68 + t + 4 - k];
    pk_store(h0pk, (size_t)b * L_SZ + t0 + t, 2 * DIM_SZ, c0 + c, acc);
  }
}

// ---- symmetric istft basis tables (window+sideband folded), packed bf16 hi/lo ----
__global__ __launch_bounds__(256) void atab2_k(ushort* __restrict__ tab,
                                               double* __restrict__ win) {
  int flat = blockIdx.x * 256 + threadIdx.x;  // over 2*640*544 = 696320
  int table = flat / ATSZ;
  int rem = flat - table * ATSZ;
  int n = rem / ATK, k = rem % ATK;
  const double W = 6.283185307179586476925287 / 1024.0;
  float val = 0.f;
  if (n <= 512 && k <= 512) {
    double wn = 0.5 * (1.0 - cos(W * (double)n));
    int mm = (k * n) & 1023;
    if (table == 0) {
      double wk = (k == 0 || k == 512) ? 1.0 : 2.0;
      val = (float)(wn * wk * cos(W * (double)mm));
    } else {
      val = (float)(wn * 2.0 * sin(W * (double)mm));
    }
  }
  pk_store(tab + (size_t)table * ATSZ_PK, (size_t)n, ATROW, k, val);
  if (flat < 1024) win[flat] = 0.5 * (1.0 - cos(W * (double)flat));
}

// ---- S prep: read fp32 (m,p) logits, emit packed Sre, Sim ----
__global__ __launch_bounds__(256) void sprep2_k(const float* __restrict__ mp,
                                                ushort* __restrict__ Sre,
                                                ushort* __restrict__ Sim) {
  size_t flat = (size_t)blockIdx.x * 256 + threadIdx.x;  // over 8*2048*544
  size_t row = flat / ATK;
  int k = (int)(flat % ATK);
  float re = 0.f, im = 0.f;
  if (k < 513) {
    const float* r = mp + row * SPADK;
    float m = r[k], p = r[513 + k];
    float mag = fminf(expf(m), 100.0f);
    re = mag * cosf(p);
    im = mag * sinf(p);
  }
  pk_store(Sre, row, ATROW, k, re);
  pk_store(Sim, row, ATROW, k, im);
}

// ---- bf16 3-term-split MFMA GEMM, 2-phase double-buffered (T3/T4-lite):
//  128x128 tile, 4 waves x (64x64), K-step 32. Stage tile k+1 while computing tile k;
//  counted s_waitcnt vmcnt(8) (the 8 prefetch DMAs stay in flight across the barrier).
//  global_load_lds(16B) staging, both-sides XOR swizzle (chunk ^ (row&7)).
//  NOTE: stage() takes the K offset in ELEMENTS (R9 bug: passed tile index -> misread).
template <bool GELU, bool OUTBF>
__global__ __launch_bounds__(256, 2) void gemm_pk(
    const ushort* __restrict__ Apk, size_t a_bs,
    const ushort* __restrict__ Bpk, size_t b_bs,
    const float* __restrict__ bias, int Mb,
    float* __restrict__ Cf, ushort* __restrict__ Cpk, size_t c_bs, int ldc,
    int Mst, int K) {
  const int b = blockIdx.z;
  const int m0 = blockIdx.x * 128;
  const int t0 = blockIdx.y * 128;
  const int tid = threadIdx.x;
  const int l = tid & 63;
  const int w = tid >> 6;
  const int wm = (w & 1) * 64;
  const int wt = (w >> 1) * 64;
  const int tr = l & 15;   // frag row within 16; also output col t
  const int ks = l >> 4;   // k-slot (8 bf16); also output row-quad selector
  __shared__ ushort As[2][128 * 64];
  __shared__ ushort Bs[2][128 * 64];
  const int pitch = 2 * K;
  const int sr = l >> 3;         // lds row within 8-row group
  const int sc = l & 7;          // lds 16B-chunk within row
  const int scs = sc ^ sr;       // pre-swizzled global chunk
  const ushort* gA = Apk + (size_t)b * a_bs + (size_t)(m0 + w * 32 + sr) * pitch + scs * 8;
  const ushort* gB = Bpk + (size_t)b * b_bs + (size_t)(t0 + w * 32 + sr) * pitch + scs * 8;
  const int swz = tr & 7;
  const int ch_hi = ((2 * ks) ^ swz) * 8;
  const int ch_lo = ((2 * ks + 1) ^ swz) * 8;
  const int aBase = (wm + tr) * 64;
  const int bBase = (wt + tr) * 64;

  auto stage = [&](int buf, int kel) {   // kel = K offset in elements
    const ushort* ga = gA + kel * 2;
    const ushort* gb = gB + kel * 2;
    ushort* la = As[buf] + w * 32 * 64;
    ushort* lb = Bs[buf] + w * 32 * 64;
#pragma unroll
    for (int i = 0; i < 4; i++) {
      gl_lds16(ga + (size_t)(i * 8) * pitch, la + i * 8 * 64);
      gl_lds16(gb + (size_t)(i * 8) * pitch, lb + i * 8 * 64);
    }
  };

  f32x4 acc[4][4];
#pragma unroll
  for (int i = 0; i < 4; i++)
#pragma unroll
    for (int j = 0; j < 4; j++) acc[i][j] = (f32x4){0.f, 0.f, 0.f, 0.f};

  const int NK = K / 32;
  stage(0, 0);                       // prologue prefetch
  int cur = 0;
  for (int ki = 0; ki < NK; ki++) {
    if (ki + 1 < NK) {
      stage(cur ^ 1, (ki + 1) * 32); // issue next tile; stays in flight
      asm volatile("s_waitcnt vmcnt(8)" ::: "memory");   // oldest 8 (tile ki) done
    } else {
      asm volatile("s_waitcnt vmcnt(0)" ::: "memory");
    }
    __builtin_amdgcn_s_barrier();    // all waves' tile-ki DMAs landed
    __builtin_amdgcn_sched_barrier(0);
    const ushort* Ac = As[cur];
    const ushort* Bc = Bs[cur];
    bfx8 ah[4], bh[4], tl[4];
#pragma unroll
    for (int f = 0; f < 4; f++) ah[f] = *(const bfx8*)(Ac + aBase + f * 1024 + ch_hi);
#pragma unroll
    for (int f = 0; f < 4; f++) bh[f] = *(const bfx8*)(Bc + bBase + f * 1024 + ch_hi);
    __builtin_amdgcn_s_setprio(1);
#pragma unroll
    for (int fi = 0; fi < 4; fi++)
#pragma unroll
      for (int fj = 0; fj < 4; fj++)
        acc[fi][fj] = __builtin_amdgcn_mfma_f32_16x16x32_bf16(ah[fi], bh[fj], acc[fi][fj], 0, 0, 0);
#pragma unroll
    for (int f = 0; f < 4; f++) tl[f] = *(const bfx8*)(Bc + bBase + f * 1024 + ch_lo);
#pragma unroll
    for (int fi = 0; fi < 4; fi++)
#pragma unroll
      for (int fj = 0; fj < 4; fj++)
        acc[fi][fj] = __builtin_amdgcn_mfma_f32_16x16x32_bf16(ah[fi], tl[fj], acc[fi][fj], 0, 0, 0);
#pragma unroll
    for (int f = 0; f < 4; f++) tl[f] = *(const bfx8*)(Ac + aBase + f * 1024 + ch_lo);
#pragma unroll
    for (int fi = 0; fi < 4; fi++)
#pragma unroll
      for (int fj = 0; fj < 4; fj++)
        acc[fi][fj] = __builtin_amdgcn_mfma_f32_16x16x32_bf16(tl[fi], bh[fj], acc[fi][fj], 0, 0, 0);
    __builtin_amdgcn_s_setprio(0);
    __builtin_amdgcn_sched_barrier(0);
    __builtin_amdgcn_s_barrier();    // reads of buf cur retired before it's re-staged
    cur ^= 1;
  }

  const int orow = ks * 4;
#pragma unroll
  for (int fi = 0; fi < 4; fi++) {
    int m = m0 + wm + fi * 16 + orow;
    if (m >= Mst) continue;
#pragma unroll
    for (int fj = 0; fj < 4; fj++) {
      int t = t0 + wt + fj * 16 + tr;
      float o[4];
#pragma unroll
      for (int i = 0; i < 4; i++) {
        float xv = acc[fi][fj][i];
        if (bias != nullptr && (m + i) < Mb) xv += bias[m + i];
        if (GELU) xv = 0.5f * xv * (1.0f + erff(xv * 0.70710678118654752f));
        o[i] = xv;
      }
      if (OUTBF) {
        size_t base = (size_t)b * c_bs + (size_t)t * (2 * ldc) + ((m >> 3) * 16 + (m & 7));
        ushort hb[4], lb[4];
#pragma unroll
        for (int i = 0; i < 4; i++) {
          float hf = bfhi_f(o[i]);
          hb[i] = (ushort)(__float_as_uint(hf) >> 16);
          lb[i] = f2bf(o[i] - hf);
        }
        *(ushort4*)(Cpk + base) = make_ushort4(hb[0], hb[1], hb[2], hb[3]);
        *(ushort4*)(Cpk + base + 8) = make_ushort4(lb[0], lb[1], lb[2], lb[3]);
      } else {
        *(float4*)(Cf + (size_t)b * c_bs + (size_t)t * ldc + m) =
            make_float4(o[0], o[1], o[2], o[3]);
      }
    }
  }
}

// ------- overlap-add + env normalize + crop, with symmetric frame reconstruction ----
__global__ __launch_bounds__(256) void ola_k(const float* __restrict__ CD,
                                             const double* __restrict__ win,
                                             float* __restrict__ out) {
  size_t flat = (size_t)blockIdx.x * 256 + threadIdx.x;  // over 8*524288
  int b = (int)(flat >> 19);
  int t = (int)(flat & 524287);
  int g = t + 384;  // PAD
  int r = g & 255, q4 = g >> 8;
  double acc = 0.0, env = 0.0;
#pragma unroll
  for (int q = 0; q < 4; q++) {
    int tau = q4 - q;
    int n = r + 256 * q;
    if (tau >= 0 && tau < 2048) {
      double w = win[n];
      int np = (n <= 512) ? n : 1024 - n;
      double sgn = (n <= 512) ? -1.0 : 1.0;
      const float* base = CD + ((size_t)b * 2048 + tau) * 1152 + np;
      acc += (double)base[0] + sgn * (double)base[576];
      env = fma(w, w, env);
    }
  }
  out[flat] = (float)(acc / (env * 1024.0));
}

extern "C" void kernel_launch(void* const* d_in, const int* in_sizes, int n_in, void* d_out,
                              int out_size, void* d_ws, size_t ws_size, hipStream_t stream) {
  (void)in_sizes; (void)n_in; (void)out_size; (void)ws_size;
  const float* x       = (const float*)d_in[0];
  const float* g_out   = (const float*)d_in[1];
  const float* dconv_w = (const float*)d_in[2];
  const float* dconv_b = (const float*)d_in[3];
  const float* p1_w    = (const float*)d_in[4];
  const float* p1_b    = (const float*)d_in[5];
  const float* p1_ain  = (const float*)d_in[6];
  const float* p1_aout = (const float*)d_in[7];
  const float* p2_w    = (const float*)d_in[8];
  const float* p2_b    = (const float*)d_in[9];
  const float* p2_ain  = (const float*)d_in[10];
  const float* p2_aout = (const float*)d_in[11];
  const float* out_w   = (const float*)d_in[12];
  const float* out_b   = (const float*)d_in[13];
  const float* out_ain = (const float*)d_in[14];
  const float* out_aout= (const float*)d_in[15];

  // Workspace: front tables + arena with time-shared slots; peak ~177 MB < proven 192.3.
  char* ws = (char*)d_ws;
  float* ain1  = (float*)(ws + 0);         // transposed [b][12][512]
  float* aout1 = (float*)(ws + 196608);
  float* ain2  = (float*)(ws + 786432);    // transposed [b][12][1536]
  float* aout2 = (float*)(ws + 1376256);
  float* ain3  = (float*)(ws + 1572864);   // transposed [b][16][512]
  float* aout3 = (float*)(ws + 1835008);
  ushort* tab  = (ushort*)(ws + 2360320);  // 2 tables * 640*1088*2 B
  double* win  = (double*)(ws + 5145600);
  char*  arena = ws + 5153792;
  ushort* h1  = (ushort*)(arena + 0);
  float*  mp  = (float*)(arena + 0);
  float*  CD  = (float*)(arena + 0);
  ushort* h0  = (ushort*)(arena + 100663296);
  ushort* h2  = (ushort*)(arena + 100663296);
  ushort* w1  = (ushort*)(arena + 134217728);
  ushort* w2  = (ushort*)(arena + 134217728);
  ushort* w3  = (ushort*)(arena + 134217728);
  ushort* Sre = (ushort*)(arena + 100663296);
  ushort* Sim = (ushort*)(arena + 136314880);

  lora_vec_k<<<1536, 256, 0, stream>>>(p1_ain, 6144, g_out, ain1, 512, 12);
  lora_vec_k<<<4608, 256, 0, stream>>>(p1_aout, 18432, g_out, aout1, 0, 0);
  lora_vec_k<<<4608, 256, 0, stream>>>(p2_ain, 18432, g_out, ain2, 1536, 12);
  lora_vec_k<<<1536, 256, 0, stream>>>(p2_aout, 6144, g_out, aout2, 0, 0);
  lora_vec_k<<<2048, 256, 0, stream>>>(out_ain, 8192, g_out, ain3, 512, 16);
  lora_vec_k<<<4104, 256, 0, stream>>>(out_aout, 16416, g_out, aout3, 0, 0);
  atab2_k<<<2720, 256, 0, stream>>>(tab, win);
  dconv_k<<<dim3(32, 8, 8), 256, 0, stream>>>(x, dconv_w, dconv_b, h0);

  // layer 1: h1 = gelu(weff1 . h0 + b1)
  weff_k<<<dim3(384, 1, 8), 256, 0, stream>>>(p1_w, ain1, aout1, w1, 1536, 1536, 512, 12);
  gemm_pk<true, true><<<dim3(12, 16, 8), 256, 0, stream>>>(
      w1, (size_t)1536 * 1024, h0, (size_t)2048 * 1024, p1_b, 1536,
      nullptr, h1, (size_t)2048 * 3072, 1536, 1536, 512);

  // layer 2: h2 = gelu(weff2 . h1 + b2)
  weff_k<<<dim3(384, 1, 8), 256, 0, stream>>>(p2_w, ain2, aout2, w2, 512, 512, 1536, 12);
  gemm_pk<true, true><<<dim3(4, 16, 8), 256, 0, stream>>>(
      w2, (size_t)512 * 3072, h1, (size_t)2048 * 3072, p2_b, 512,
      nullptr, h2, (size_t)2048 * 1024, 512, 512, 1536);

  // output projection: mp = weff3 . h2 + out_b  (fp32 out)
  weff_k<<<dim3(288, 1, 8), 256, 0, stream>>>(out_w, ain3, aout3, w3, 1026, 1152, 512, 16);
  gemm_pk<false, false><<<dim3(9, 16, 8), 256, 0, stream>>>(
      w3, (size_t)1152 * 1024, h2, (size_t)2048 * 1024, out_b, 1026,
      mp, nullptr, (size_t)2048 * SPADK, SPADK, SPADK, 512);

  sprep2_k<<<34816, 256, 0, stream>>>(mp, Sre, Sim);
  // cos-part -> CD[:, :, 0:576], sin-part -> CD[:, :, 576:1152]
  gemm_pk<false, false><<<dim3(5, 16, 8), 256, 0, stream>>>(
      tab, (size_t)0, Sre, (size_t)2048 * ATROW, nullptr, 0,
      CD, nullptr, (size_t)2048 * 1152, 1152, ATMV, ATK);
  gemm_pk<false, false><<<dim3(5, 16, 8), 256, 0, stream>>>(
      tab + ATSZ_PK, (size_t)0, Sim, (size_t)2048 * ATROW, nullptr, 0,
      CD + 576, nullptr, (size_t)2048 * 1152, 1152, ATMV, ATK);
  ola_k<<<16384, 256, 0, stream>>>(CD, win, (float*)d_out);
}